// Round 1
// baseline (863.528 us; speedup 1.0000x reference)
//
#include <hip/hip_runtime.h>
#include <hip/hip_bf16.h>

// GCN 3-layer pipeline on MI355X.
// Strategy: out = A·(relu(BN(A·(relu(BN(A·(X@W1)))@W2)))@W3) + b3
//   (GEMM before SpMM: A·(X@W) == (A·X)@W; bias added after final SpMM)
// CSR built per call (ws is re-poisoned) and reused across all 3 SpMMs.

#define NPART 128  // stat partial partitions (avoid same-address atomic serialization)

// ---------------- CSR build ----------------

__global__ void hist_k(const int* __restrict__ dst, int* __restrict__ cnt, int E) {
    int e = blockIdx.x * 256 + threadIdx.x;
    if (e < E) atomicAdd(&cnt[dst[e]], 1);
}

__global__ __launch_bounds__(1024) void scan1_k(const int* __restrict__ cnt,
                                                int* __restrict__ rowptr,
                                                int* __restrict__ bsum, int n) {
    __shared__ int wsum[16];
    int tid = threadIdx.x;
    int i0 = blockIdx.x * 2048 + tid * 2;
    int a0 = (i0 < n) ? cnt[i0] : 0;
    int a1 = (i0 + 1 < n) ? cnt[i0 + 1] : 0;
    int s = a0 + a1;
    int inc = s;
    int lane = tid & 63;
    #pragma unroll
    for (int d = 1; d < 64; d <<= 1) {
        int t = __shfl_up(inc, d);
        if (lane >= d) inc += t;
    }
    int wid = tid >> 6;
    if (lane == 63) wsum[wid] = inc;
    __syncthreads();
    if (tid < 16) {
        int v = wsum[tid];
        int iw = v;
        #pragma unroll
        for (int d = 1; d < 16; d <<= 1) {
            int t = __shfl_up(iw, d, 16);
            if (tid >= d) iw += t;
        }
        wsum[tid] = iw - v;  // exclusive wave offset
    }
    __syncthreads();
    int off = wsum[wid] + inc - s;  // exclusive prefix for element i0 within block
    if (i0 < n) rowptr[i0 + 1] = off + a0;
    if (i0 + 1 < n) rowptr[i0 + 2] = off + s;
    if (tid == 1023) bsum[blockIdx.x] = wsum[15] + inc;
}

__global__ void scan2_k(int* __restrict__ bsum, int nb) {
    int tid = threadIdx.x;  // 64 threads, nb <= 64
    int v = (tid < nb) ? bsum[tid] : 0;
    int inc = v;
    #pragma unroll
    for (int d = 1; d < 64; d <<= 1) {
        int t = __shfl_up(inc, d);
        if (tid >= d) inc += t;
    }
    if (tid < nb) bsum[tid] = inc - v;  // exclusive
}

__global__ void scan3_k(int* __restrict__ rowptr, int* __restrict__ cursor,
                        const int* __restrict__ bsum, int n) {
    int i = blockIdx.x * 256 + threadIdx.x;
    if (i < n) {
        int vf = rowptr[i + 1] + bsum[i >> 11];
        rowptr[i + 1] = vf;
        cursor[i + 1] = vf;
        if (i == 0) { rowptr[0] = 0; cursor[0] = 0; }
    }
}

__global__ void fill_k(const int* __restrict__ src, const int* __restrict__ dst,
                       const float* __restrict__ ew, int* __restrict__ cursor,
                       int* __restrict__ col, float* __restrict__ val, int E) {
    int e = blockIdx.x * 256 + threadIdx.x;
    if (e < E) {
        int v = dst[e];
        int p = atomicAdd(&cursor[v], 1);
        col[p] = src[e];
        val[p] = ew[e];
    }
}

// ---------------- GEMM: Y[M x NC] = f(A[M x 128]) @ W[128 x NC] ----------------
// f = identity, or fused BN+ReLU per input channel k: relu(a*scale[k]+shift[k]).
// Block: 256 threads, 64-row tile, K chunked by 32. A staged transposed in LDS.

template <int NC>
__global__ __launch_bounds__(256) void gemm_bn_k(
    const float* __restrict__ A, const float* __restrict__ W, float* __restrict__ Y,
    int M, const float* __restrict__ scale, const float* __restrict__ shift) {
    constexpr int CGB = (NC == 128) ? 5 : 4;   // col-group bits
    constexpr int NCG = 1 << CGB;              // 32 or 16 col groups (4 cols each)
    constexpr int RPT = 1 << (CGB - 2);        // rows per thread: 8 or 4 (tile = 64 rows)
    __shared__ float At[32][68];               // [k][row], 68*4B = 17*16B: b128-aligned rows
    __shared__ float Wl[32][NC];

    int tid = threadIdx.x;
    int cg = tid & (NCG - 1);
    int rg = tid >> CGB;
    int row0 = blockIdx.x * 64;

    float acc[RPT][4];
    #pragma unroll
    for (int r = 0; r < RPT; ++r)
        #pragma unroll
        for (int j = 0; j < 4; ++j) acc[r][j] = 0.f;

    for (int kc = 0; kc < 4; ++kc) {
        // stage A chunk (64 rows x 32 k), transposed, BN+ReLU fused
        #pragma unroll
        for (int t = 0; t < 2; ++t) {
            int i = tid + t * 256;
            int r = i >> 3, fc = i & 7;
            int grow = row0 + r;
            int gk = kc * 32 + fc * 4;
            float4 a = make_float4(0.f, 0.f, 0.f, 0.f);
            if (grow < M) a = *(const float4*)&A[(size_t)grow * 128 + gk];
            if (scale) {
                a.x = fmaxf(a.x * scale[gk + 0] + shift[gk + 0], 0.f);
                a.y = fmaxf(a.y * scale[gk + 1] + shift[gk + 1], 0.f);
                a.z = fmaxf(a.z * scale[gk + 2] + shift[gk + 2], 0.f);
                a.w = fmaxf(a.w * scale[gk + 3] + shift[gk + 3], 0.f);
            }
            At[fc * 4 + 0][r] = a.x;
            At[fc * 4 + 1][r] = a.y;
            At[fc * 4 + 2][r] = a.z;
            At[fc * 4 + 3][r] = a.w;
        }
        // stage W chunk (32 k x NC)
        constexpr int NF4 = 8 * NC;  // float4 count
        for (int i = tid; i < NF4; i += 256) {
            int k = i / (NC / 4);
            int c4 = i % (NC / 4);
            *(float4*)&Wl[k][c4 * 4] = *(const float4*)&W[(size_t)(kc * 32 + k) * NC + c4 * 4];
        }
        __syncthreads();
        if (cg * 4 < NC) {
            #pragma unroll
            for (int k = 0; k < 32; ++k) {
                float4 w = *(const float4*)&Wl[k][cg * 4];
                #pragma unroll
                for (int rb = 0; rb < RPT; rb += 4) {
                    float4 a = *(const float4*)&At[k][rg * RPT + rb];
                    acc[rb + 0][0] += a.x * w.x; acc[rb + 0][1] += a.x * w.y;
                    acc[rb + 0][2] += a.x * w.z; acc[rb + 0][3] += a.x * w.w;
                    acc[rb + 1][0] += a.y * w.x; acc[rb + 1][1] += a.y * w.y;
                    acc[rb + 1][2] += a.y * w.z; acc[rb + 1][3] += a.y * w.w;
                    acc[rb + 2][0] += a.z * w.x; acc[rb + 2][1] += a.z * w.y;
                    acc[rb + 2][2] += a.z * w.z; acc[rb + 2][3] += a.z * w.w;
                    acc[rb + 3][0] += a.w * w.x; acc[rb + 3][1] += a.w * w.y;
                    acc[rb + 3][2] += a.w * w.z; acc[rb + 3][3] += a.w * w.w;
                }
            }
        }
        __syncthreads();
    }
    if (cg * 4 < NC) {
        #pragma unroll
        for (int r = 0; r < RPT; ++r) {
            int grow = row0 + rg * RPT + r;
            if (grow < M) {
                float4 o = make_float4(acc[r][0], acc[r][1], acc[r][2], acc[r][3]);
                *(float4*)&Y[(size_t)grow * NC + cg * 4] = o;
            }
        }
    }
}

// ---------------- SpMM (gather-CSR): H[v] = sum_e val[e] * X[col[e]] ----------------
// One wave per node; channels across lanes. Optional fused BN-stat partials + bias.

template <int NC>
__global__ __launch_bounds__(256) void spmm_k(
    const int* __restrict__ rowptr, const int* __restrict__ col, const float* __restrict__ val,
    const float* __restrict__ X, float* __restrict__ H, int n,
    float* __restrict__ psum, float* __restrict__ psq, const float* __restrict__ bias) {
    __shared__ float lsum[NC];
    __shared__ float lsq[NC];
    const bool doStats = (psum != nullptr);
    if (doStats) {
        for (int i = threadIdx.x; i < NC; i += 256) { lsum[i] = 0.f; lsq[i] = 0.f; }
        __syncthreads();
    }
    int lane = threadIdx.x & 63;
    int v = blockIdx.x * 4 + (threadIdx.x >> 6);
    if (v < n) {
        int s = rowptr[v], e = rowptr[v + 1];
        if (NC == 128) {
            float2 acc = {0.f, 0.f};
            int i = s;
            for (; i + 4 <= e; i += 4) {
                int u0 = col[i], u1 = col[i + 1], u2 = col[i + 2], u3 = col[i + 3];
                float w0 = val[i], w1 = val[i + 1], w2 = val[i + 2], w3 = val[i + 3];
                float2 x0 = *(const float2*)&X[(size_t)u0 * 128 + 2 * lane];
                float2 x1 = *(const float2*)&X[(size_t)u1 * 128 + 2 * lane];
                float2 x2 = *(const float2*)&X[(size_t)u2 * 128 + 2 * lane];
                float2 x3 = *(const float2*)&X[(size_t)u3 * 128 + 2 * lane];
                acc.x += w0 * x0.x; acc.y += w0 * x0.y;
                acc.x += w1 * x1.x; acc.y += w1 * x1.y;
                acc.x += w2 * x2.x; acc.y += w2 * x2.y;
                acc.x += w3 * x3.x; acc.y += w3 * x3.y;
            }
            for (; i < e; ++i) {
                int u = col[i]; float wv = val[i];
                float2 x = *(const float2*)&X[(size_t)u * 128 + 2 * lane];
                acc.x += wv * x.x; acc.y += wv * x.y;
            }
            *(float2*)&H[(size_t)v * 128 + 2 * lane] = acc;
            if (doStats) {
                atomicAdd(&lsum[2 * lane + 0], acc.x);
                atomicAdd(&lsum[2 * lane + 1], acc.y);
                atomicAdd(&lsq[2 * lane + 0], acc.x * acc.x);
                atomicAdd(&lsq[2 * lane + 1], acc.y * acc.y);
            }
        } else {
            float acc = 0.f;
            bool al = lane < NC;
            int i = s;
            for (; i + 4 <= e; i += 4) {
                int u0 = col[i], u1 = col[i + 1], u2 = col[i + 2], u3 = col[i + 3];
                float w0 = val[i], w1 = val[i + 1], w2 = val[i + 2], w3 = val[i + 3];
                if (al) {
                    float x0 = X[(size_t)u0 * NC + lane];
                    float x1 = X[(size_t)u1 * NC + lane];
                    float x2 = X[(size_t)u2 * NC + lane];
                    float x3 = X[(size_t)u3 * NC + lane];
                    acc += w0 * x0; acc += w1 * x1; acc += w2 * x2; acc += w3 * x3;
                }
            }
            for (; i < e; ++i) {
                int u = col[i]; float wv = val[i];
                if (al) acc += wv * X[(size_t)u * NC + lane];
            }
            if (al) H[(size_t)v * NC + lane] = acc + (bias ? bias[lane] : 0.f);
        }
    }
    if (doStats) {
        __syncthreads();
        int p = blockIdx.x & (NPART - 1);
        for (int i = threadIdx.x; i < NC; i += 256) {
            atomicAdd(&psum[p * NC + i], lsum[i]);
            atomicAdd(&psq[p * NC + i], lsq[i]);
        }
    }
}

// ---------------- BN stats -> scale/shift ----------------

__global__ void bnstats_k(const float* __restrict__ ps, const float* __restrict__ pq,
                          const float* __restrict__ gamma, const float* __restrict__ beta,
                          float* __restrict__ scale, float* __restrict__ shift, int n) {
    int c = threadIdx.x;  // 128 threads
    float s = 0.f, q = 0.f;
    for (int p = 0; p < NPART; ++p) {
        s += ps[p * 128 + c];
        q += pq[p * 128 + c];
    }
    float mean = s / (float)n;
    float var = q / (float)n - mean * mean;
    float sc = gamma[c] / sqrtf(var + 1e-5f);
    scale[c] = sc;
    shift[c] = beta[c] - mean * sc;
}

// ---------------- launch ----------------

extern "C" void kernel_launch(void* const* d_in, const int* in_sizes, int n_in,
                              void* d_out, int out_size, void* d_ws, size_t ws_size,
                              hipStream_t stream) {
    const float* feat = (const float*)d_in[0];
    const int* esrc   = (const int*)d_in[1];
    const int* edst   = (const int*)d_in[2];
    const float* ew   = (const float*)d_in[3];
    const float* W1   = (const float*)d_in[4];
    const float* W2   = (const float*)d_in[5];
    const float* W3   = (const float*)d_in[6];
    const float* b3   = (const float*)d_in[7];
    const float* g1   = (const float*)d_in[8];
    const float* be1  = (const float*)d_in[9];
    const float* g2   = (const float*)d_in[10];
    const float* be2  = (const float*)d_in[11];
    float* out = (float*)d_out;

    const int N = in_sizes[0] / 128;
    const int E = in_sizes[1];

    char* w = (char*)d_ws;
    size_t o = 0;
    auto alloc = [&](size_t b) { size_t r = o; o = (o + b + 255) & ~(size_t)255; return r; };
    int* rowptr   = (int*)(w + alloc((size_t)(N + 1) * 4));
    int* cursor   = (int*)(w + alloc((size_t)(N + 1) * 4));
    int* cnt      = (int*)(w + alloc((size_t)N * 4));
    int* bsum     = (int*)(w + alloc(64 * 4));
    int* col      = (int*)(w + alloc((size_t)E * 4));
    float* val    = (float*)(w + alloc((size_t)E * 4));
    float* stats  = (float*)(w + alloc((size_t)4 * NPART * 128 * 4));
    float* sc1    = (float*)(w + alloc(128 * 4));
    float* sh1    = (float*)(w + alloc(128 * 4));
    float* sc2    = (float*)(w + alloc(128 * 4));
    float* sh2    = (float*)(w + alloc(128 * 4));
    float* Y      = (float*)(w + alloc((size_t)N * 128 * 4));
    float* H      = (float*)(w + alloc((size_t)N * 128 * 4));
    float* p1s = stats;
    float* p1q = stats + NPART * 128;
    float* p2s = stats + 2 * NPART * 128;
    float* p2q = stats + 3 * NPART * 128;

    hipMemsetAsync(cnt, 0, (size_t)N * 4, stream);
    hipMemsetAsync(stats, 0, (size_t)4 * NPART * 128 * 4, stream);

    // CSR build (reused by all 3 SpMMs)
    hist_k<<<(E + 255) / 256, 256, 0, stream>>>(edst, cnt, E);
    int nb = (N + 2047) / 2048;
    scan1_k<<<nb, 1024, 0, stream>>>(cnt, rowptr, bsum, N);
    scan2_k<<<1, 64, 0, stream>>>(bsum, nb);
    scan3_k<<<(N + 255) / 256, 256, 0, stream>>>(rowptr, cursor, bsum, N);
    fill_k<<<(E + 255) / 256, 256, 0, stream>>>(esrc, edst, ew, cursor, col, val, E);

    int gb = (N + 63) / 64;
    int sb = (N + 3) / 4;

    // layer 1: Y1 = feat@W1 ; H1 = A*Y1 (+stats)
    gemm_bn_k<128><<<gb, 256, 0, stream>>>(feat, W1, Y, N, nullptr, nullptr);
    spmm_k<128><<<sb, 256, 0, stream>>>(rowptr, col, val, Y, H, N, p1s, p1q, nullptr);
    bnstats_k<<<1, 128, 0, stream>>>(p1s, p1q, g1, be1, sc1, sh1, N);

    // layer 2: Y2 = relu(BN(H1))@W2 ; H2 = A*Y2 (+stats)
    gemm_bn_k<128><<<gb, 256, 0, stream>>>(H, W2, Y, N, sc1, sh1);
    spmm_k<128><<<sb, 256, 0, stream>>>(rowptr, col, val, Y, H, N, p2s, p2q, nullptr);
    bnstats_k<<<1, 128, 0, stream>>>(p2s, p2q, g2, be2, sc2, sh2, N);

    // layer 3: Y3 = relu(BN(H2))@W3 ; out = A*Y3 + b3
    gemm_bn_k<40><<<gb, 256, 0, stream>>>(H, W3, Y, N, sc2, sh2);
    spmm_k<40><<<sb, 256, 0, stream>>>(rowptr, col, val, Y, out, N, nullptr, nullptr, b3);
}